// Round 1
// baseline (99.972 us; speedup 1.0000x reference)
//
#include <hip/hip_runtime.h>
#include <hip/hip_bf16.h>

// UncompressTransformLayer: scatter compressed strict-upper-triangular vector
// (row-major triu order, k=1) into a dense [n,n] fp32 matrix, zeros elsewhere.
// n = 8192, m = n*(n-1)/2 = 33,550,336.
//
// Memory-bound: must write all n*n = 64M floats (256 MiB) each call (harness
// poisons d_out once and never re-poisons), read 128 MiB compressed.
// Floor ~ 402 MB / 6.3 TB/s ~ 64 us.

#define N_DIM 8192
#define QUADS_PER_ROW (N_DIM / 4)          // 2048
#define TOTAL_QUADS ((long long)N_DIM * QUADS_PER_ROW)  // 16,777,216

__global__ void __launch_bounds__(256)
uncompress_kernel(const float* __restrict__ comp, float* __restrict__ out) {
    const unsigned stride = gridDim.x * blockDim.x;
    for (unsigned q = blockIdx.x * blockDim.x + threadIdx.x;
         q < (unsigned)TOTAL_QUADS; q += stride) {
        const unsigned i  = q >> 11;          // row  (q / 2048)
        const unsigned j0 = (q & 2047u) << 2; // starting column of this quad

        float4 v;
        if (j0 + 3u <= i) {
            // entire quad at/below diagonal -> zeros
            v = make_float4(0.f, 0.f, 0.f, 0.f);
        } else {
            // compressed index for (i, j) with j > i:
            //   idx = Offset(i) + (j - i - 1),  Offset(i) = i*(n-1) - i*(i-1)/2
            // base = Offset(i) - i - 1  (so idx = base + j). All fits in u32.
            const unsigned off  = i * (N_DIM - 1) - ((i * (i - 1u)) >> 1);
            const unsigned base = off - i - 1u;   // may "underflow" for i=0,
                                                  // but only used where j > i
            if (j0 > i) {
                // fully above diagonal: 4 contiguous compressed reads
                const float* p = comp + (base + j0);
                v.x = p[0]; v.y = p[1]; v.z = p[2]; v.w = p[3];
            } else {
                // straddles the diagonal: per-element predication
                v.x = (j0 + 0u > i) ? comp[base + j0 + 0u] : 0.f;
                v.y = (j0 + 1u > i) ? comp[base + j0 + 1u] : 0.f;
                v.z = (j0 + 2u > i) ? comp[base + j0 + 2u] : 0.f;
                v.w = (j0 + 3u > i) ? comp[base + j0 + 3u] : 0.f;
            }
        }
        // coalesced 16B store; row-major out index = i*n + j0 (16B-aligned)
        *reinterpret_cast<float4*>(out + ((size_t)i << 13) + j0) = v;
    }
}

extern "C" void kernel_launch(void* const* d_in, const int* in_sizes, int n_in,
                              void* d_out, int out_size, void* d_ws, size_t ws_size,
                              hipStream_t stream) {
    const float* comp = (const float*)d_in[0];
    float* out = (float*)d_out;

    // memory-bound: cap grid and grid-stride (G11). 2048 blocks x 256 threads
    // -> each thread handles 32 quads.
    const int block = 256;
    const int grid  = 2048;
    uncompress_kernel<<<grid, block, 0, stream>>>(comp, out);
}